// Round 5
// baseline (102.145 us; speedup 1.0000x reference)
//
#include <hip/hip_runtime.h>
#include <hip/hip_bf16.h>

// ShuffleNet fused block-MLP, MI355X (gfx950).  R5: wave-autonomous fused kernel.
// x:(8192,1024) f32; w1:(16,256,64); b1:(4096); w2:(16,64,256); b2:(1024); y f32.
//   h[b,n,o] = sum_i x[b,n*64+i]*w1[n,o,i];  shuffled j = o*16+n
//   g = gelu(h+b1);  y[b,np*64+o'] = sum_{i'} g[b,np*256+i']*w2[np,o',i'] + b2
//   i' = n*16 + ohi  with  o = np*16 + ohi.
// Each wave owns 16 rows and one n'-quarter (4 np values). Per np: GEMM1 over
// all 16 n (weights from L2, shared across the WG's 4 waves via L1), GELU,
// write 16x256 chunk to a PRIVATE 8KB LDS region (same-wave -> NO barrier),
// read back as GEMM2 A-frags (ds_read_b128), GEMM2, store y. Zero barriers,
// zero cross-wave deps; 2048 independent waves (2/SIMD, all co-resident).
// LDS XOR swizzle: short-col ^ ((l15&7)<<3) -> uniform banks for b64 w / b128 r.
// blockIdx: q = b>>7 (quarter), rt = (b&127)*4 + wave -> the 4 WGs touching the
// same x rows are b, b+128, b+256, b+384 == same XCD (mod 8) -> x L2 locality.

typedef __attribute__((ext_vector_type(8))) short  short8;   // 8 bf16 = 4 VGPR
typedef __attribute__((ext_vector_type(4))) short  short4v;
typedef __attribute__((ext_vector_type(4))) float  floatx4;

__device__ __forceinline__ short f2bf(float f) {
  union { __hip_bfloat16 h; short s; } u;
  u.h = __float2bfloat16(f);
  return u.s;
}

// gelu(v) ~= v * sigmoid(1.5957691*(v + 0.044715 v^3)) (abs err < 5e-4)
__device__ __forceinline__ float gelu_f(float v) {
  float v2 = v * v;
  float p  = fmaf(0.044715f, v2, 1.0f);
  float t  = v * p;
  float e  = __expf(-1.5957691f * t);
  return v * __builtin_amdgcn_rcpf(1.0f + e);
}

// ---- one pack kernel: w1 frags | w2 frags | b1 frags ----
// w1 frag (n,np,ks): lane l elem e = w1[n][np*16+(l&15)][ks*32+(l>>4)*8+e]
// w2 frag (np,ks,ot): lane l elem e: k=ks*32+(l>>4)*8+e; value =
//                     w2[np][ot*16+(l&15)][(k&15)*16+(k>>4)]
// b1 frag (n,np): lane l reg r = b1[(np*16+(l>>4)*4+r)*16+n]
__global__ void pack_k(const float* __restrict__ w1, const float* __restrict__ w2,
                       const float* __restrict__ b1, short* __restrict__ w1p,
                       short* __restrict__ w2p, float* __restrict__ b1p) {
  const int t = blockIdx.x * blockDim.x + threadIdx.x;  // 160*512 = 81920
  const int lane = t & 63;
  const int lhi = lane >> 4;
  if (t < 32768) {  // w1
    const int ks = (t >> 6) & 1, np = (t >> 7) & 15, n = (t >> 11) & 15;
    const float* src = w1 + ((size_t)(n * 256 + np * 16 + (lane & 15)) * 64 + ks * 32 + lhi * 8);
    short8 f;
#pragma unroll
    for (int e = 0; e < 8; ++e) f[e] = f2bf(src[e]);
    *(short8*)(w1p + (size_t)t * 8) = f;
  } else if (t < 65536) {  // w2
    const int t2 = t - 32768;
    const int ot = (t2 >> 6) & 3, ks = (t2 >> 8) & 7, np = (t2 >> 11) & 15;
    const int op = ot * 16 + (lane & 15);
    short8 f;
#pragma unroll
    for (int e = 0; e < 8; ++e) {
      const int k = ks * 32 + lhi * 8 + e;
      f[e] = f2bf(w2[(size_t)(np * 64 + op) * 256 + (k & 15) * 16 + (k >> 4)]);
    }
    *(short8*)(w2p + (size_t)t2 * 8) = f;
  } else {  // b1
    const int t3 = t - 65536;  // 16384
    const int np = (t3 >> 6) & 15, n = (t3 >> 10) & 15;
    floatx4 b;
#pragma unroll
    for (int r = 0; r < 4; ++r) b[r] = b1[(np * 16 + lhi * 4 + r) * 16 + n];
    *(floatx4*)(b1p + (size_t)((n * 16 + np) * 64 + lane) * 4) = b;
  }
}

// ---- fused: 512 WGs x 256 thr (4 waves); wave = (rt, quarter q) ----
__global__ __launch_bounds__(256, 2) void fused_k(
    const float* __restrict__ x, const short* __restrict__ w1p,
    const short* __restrict__ w2p, const float* __restrict__ b1p,
    const float* __restrict__ b2, float* __restrict__ y) {
  __shared__ __align__(16) short chunk[4 * 4096];  // 8KB per wave, private

  const int tid = threadIdx.x;
  const int wv = tid >> 6, lane = tid & 63;
  const int l15 = lane & 15, lhi = lane >> 4;
  const int q  = blockIdx.x >> 7;               // n'-quarter 0..3
  const int rt = (blockIdx.x & 127) * 4 + wv;   // rowtile 0..511
  short* myc = chunk + wv * 4096;
  const int swz = (l15 & 7) << 3;

  // x fragments: all 16 n-blocks, 2 ksteps (B-operand: l15 = row, k = lhi*8+e)
  short8 xf[16][2];
#pragma unroll
  for (int n = 0; n < 16; ++n) {
#pragma unroll
    for (int ks = 0; ks < 2; ++ks) {
      const float* px = x + (size_t)(rt * 16 + l15) * 1024 + n * 64 + ks * 32 + lhi * 8;
      floatx4 a = *(const floatx4*)px;
      floatx4 b = *(const floatx4*)(px + 4);
      short8 f;
#pragma unroll
      for (int e = 0; e < 4; ++e) { f[e] = f2bf(a[e]); f[e + 4] = f2bf(b[e]); }
      xf[n][ks] = f;
    }
  }

  for (int it = 0; it < 4; ++it) {
    const int np = q * 4 + it;

    // ---- GEMM1 over 16 n-blocks; gelu; scatter into private LDS chunk ----
#pragma unroll
    for (int n = 0; n < 16; ++n) {
      short8 wf0 = *(const short8*)(w1p + (size_t)(((n * 16 + np) * 2 + 0) * 64 + lane) * 8);
      short8 wf1 = *(const short8*)(w1p + (size_t)(((n * 16 + np) * 2 + 1) * 64 + lane) * 8);
      floatx4 bias = *(const floatx4*)(b1p + (size_t)((n * 16 + np) * 64 + lane) * 4);
      floatx4 acc = {0.f, 0.f, 0.f, 0.f};
      acc = __builtin_amdgcn_mfma_f32_16x16x32_bf16(wf0, xf[n][0], acc, 0, 0, 0);
      acc = __builtin_amdgcn_mfma_f32_16x16x32_bf16(wf1, xf[n][1], acc, 0, 0, 0);
      short4v hv;
#pragma unroll
      for (int r = 0; r < 4; ++r)
        hv[r] = f2bf(gelu_f(acc[r] + bias[r]));
      // chunk[row=l15][i' = n*16 + lhi*4 + r], XOR-swizzled
      *(short4v*)(&myc[l15 * 256 + ((n * 16 + lhi * 4) ^ swz)]) = hv;
    }

    // ---- read back GEMM2 A-frags (same wave: no barrier, just lgkm order) ----
    short8 af[8];
#pragma unroll
    for (int ks = 0; ks < 8; ++ks)
      af[ks] = *(const short8*)(&myc[l15 * 256 + ((ks * 32 + lhi * 8) ^ swz)]);

    // ---- GEMM2: y[:, np*64 .. +64) ----
#pragma unroll
    for (int ot = 0; ot < 4; ++ot) {
      floatx4 a0 = {0.f, 0.f, 0.f, 0.f}, a1 = {0.f, 0.f, 0.f, 0.f};
#pragma unroll
      for (int ks = 0; ks < 8; ks += 2) {
        short8 b0  = *(const short8*)(w2p + (size_t)(((np * 8 + ks) * 4 + ot) * 64 + lane) * 8);
        short8 b1f = *(const short8*)(w2p + (size_t)(((np * 8 + ks + 1) * 4 + ot) * 64 + lane) * 8);
        a0 = __builtin_amdgcn_mfma_f32_16x16x32_bf16(af[ks], b0, a0, 0, 0, 0);
        a1 = __builtin_amdgcn_mfma_f32_16x16x32_bf16(af[ks + 1], b1f, a1, 0, 0, 0);
      }
      const int col = np * 64 + ot * 16 + l15;
      const float bb = b2[col];
      float* py = y + (size_t)(rt * 16 + lhi * 4) * 1024 + col;
#pragma unroll
      for (int r = 0; r < 4; ++r)
        py[(size_t)r * 1024] = a0[r] + a1[r] + bb;
    }
  }
}

extern "C" void kernel_launch(void* const* d_in, const int* in_sizes, int n_in,
                              void* d_out, int out_size, void* d_ws, size_t ws_size,
                              hipStream_t stream) {
  const float* x  = (const float*)d_in[0];
  const float* w1 = (const float*)d_in[1];
  const float* b1 = (const float*)d_in[2];
  const float* w2 = (const float*)d_in[3];
  const float* b2 = (const float*)d_in[4];
  float* y = (float*)d_out;

  short* w1p = (short*)d_ws;                   // 512 KB
  short* w2p = w1p + 16 * 256 * 64;            // 512 KB
  float* b1p = (float*)(w2p + 16 * 256 * 64);  // 256 KB

  pack_k<<<160, 512, 0, stream>>>(w1, w2, b1, w1p, w2p, b1p);
  fused_k<<<512, 256, 0, stream>>>(x, w1p, w2p, b1p, b2, y);
}

// Round 6
// 50.446 us; speedup vs baseline: 2.0248x; 2.0248x over previous
//
#include <hip/hip_runtime.h>
#include <hip/hip_bf16.h>

// ShuffleNet fused block-MLP, MI355X (gfx950).  R6: 2-kernel split, k1 loop-flipped
// so WEIGHTS ARE REGISTER-RESIDENT and rows stream (no in-loop dependent loads).
// x:(8192,1024) f32; w1:(16,256,64); b1:(4096); w2:(16,64,256); b2:(1024); y f32.
//   h[b,n,o] = sum_i x[b,n*64+i]*w1[n,o,i];  shuffled j = o*16+n
//   g = gelu(h+b1);  y[b,np*64+o'] = sum_{i'} g[b,np*256+i']*w2[np,o',i'] + b2
//   i' = n*16 + ohi  with  o = np*16 + ohi.
// G layout (shorts): G[rt][np][n][row16][ohi16]; strides 65536/4096/256/16/1.
// k1: wave owns (n, np-half); 8 w1-frags (64 VGPR) + bf16 bias (16 VGPR) loaded
//     ONCE; streams 4 rowtiles x 8 np of {2 MFMA, gelu, 512B store}. x loads are
//     the only in-loop loads and are iteration-independent -> deep prefetch.
// k2: unchanged from R4 (measured ~11-12us, ~roofline).

typedef __attribute__((ext_vector_type(8))) short  short8;   // 8 bf16 = 4 VGPR
typedef __attribute__((ext_vector_type(4))) short  short4v;
typedef __attribute__((ext_vector_type(4))) float  floatx4;

__device__ __forceinline__ short f2bf(float f) {
  union { __hip_bfloat16 h; short s; } u;
  u.h = __float2bfloat16(f);
  return u.s;
}
__device__ __forceinline__ float bf2f(short s) {
  union { float f; unsigned u; } uu;
  uu.u = ((unsigned)(unsigned short)s) << 16;
  return uu.f;
}

// gelu(v) ~= v * sigmoid(1.5957691*(v + 0.044715 v^3)) (abs err < 5e-4)
// exp2-folded: sigmoid(z) = 1/(1+2^(-1.442695*z))
__device__ __forceinline__ float gelu_f(float v) {
  float v2 = v * v;
  float p  = fmaf(0.044715f, v2, 1.0f);
  float t  = v * p;
  float e  = __builtin_amdgcn_exp2f(-2.3020807f * t);   // 2^(-1.5957691*1.442695*t)
  return v * __builtin_amdgcn_rcpf(1.0f + e);
}

// ---- one pack kernel: w1 frags | w2 frags | b1 frags (bf16) ----
// w1 frag (n,np,ks): lane l elem e = w1[n][np*16+(l&15)][ks*32+(l>>4)*8+e]
// w2 frag (np,ks,ot): lane l elem e: k=ks*32+(l>>4)*8+e; value =
//                     w2[np][ot*16+(l&15)][(k&15)*16+(k>>4)]
// b1 frag (n,np): lane l reg r = bf16(b1[(np*16+(l>>4)*4+r)*16+n])
__global__ void pack_k(const float* __restrict__ w1, const float* __restrict__ w2,
                       const float* __restrict__ b1, short* __restrict__ w1p,
                       short* __restrict__ w2p, short* __restrict__ b1p) {
  const int t = blockIdx.x * blockDim.x + threadIdx.x;  // 160*512 = 81920
  const int lane = t & 63;
  const int lhi = lane >> 4;
  if (t < 32768) {  // w1
    const int ks = (t >> 6) & 1, np = (t >> 7) & 15, n = (t >> 11) & 15;
    const float* src = w1 + ((size_t)(n * 256 + np * 16 + (lane & 15)) * 64 + ks * 32 + lhi * 8);
    short8 f;
#pragma unroll
    for (int e = 0; e < 8; ++e) f[e] = f2bf(src[e]);
    *(short8*)(w1p + (size_t)t * 8) = f;
  } else if (t < 65536) {  // w2
    const int t2 = t - 32768;
    const int ot = (t2 >> 6) & 3, ks = (t2 >> 8) & 7, np = (t2 >> 11) & 15;
    const int op = ot * 16 + (lane & 15);
    short8 f;
#pragma unroll
    for (int e = 0; e < 8; ++e) {
      const int k = ks * 32 + lhi * 8 + e;
      f[e] = f2bf(w2[(size_t)(np * 64 + op) * 256 + (k & 15) * 16 + (k >> 4)]);
    }
    *(short8*)(w2p + (size_t)t2 * 8) = f;
  } else {  // b1 -> bf16 frags
    const int t3 = t - 65536;  // 16384
    const int np = (t3 >> 6) & 15, n = (t3 >> 10) & 15;
    short4v b;
#pragma unroll
    for (int r = 0; r < 4; ++r) b[r] = f2bf(b1[(np * 16 + lhi * 4 + r) * 16 + n]);
    *(short4v*)(b1p + (size_t)((n * 16 + np) * 64 + lane) * 4) = b;
  }
}

// ---- K1: x -> g (packed). 1024 WGs x 256 thr; wave = (n, np-half, rtgroup).
// Weights register-resident; 4 rowtiles streamed. ----
__global__ __launch_bounds__(256, 3) void k1_gemm1(
    const float* __restrict__ x, const short* __restrict__ w1p,
    const short* __restrict__ b1p, short* __restrict__ G) {
  const int tid = threadIdx.x;
  const int wv = tid >> 6, lane = tid & 63;
  const int l15 = lane & 15, lhi = lane >> 4;
  const int b   = blockIdx.x;                 // 0..1023
  const int rtg = b & 127;                    // rowtile group (4 rowtiles)
  const int n   = ((b >> 7) << 1) | (wv >> 1);
  const int np0 = (wv & 1) * 8;

  // one-time: weights + bias for this wave's 8 np values (resident)
  short8  wf[8][2];
  short4v bv[8];
#pragma unroll
  for (int j = 0; j < 8; ++j) {
    const int np = np0 + j;
    wf[j][0] = *(const short8*)(w1p + (size_t)(((n * 16 + np) * 2 + 0) * 64 + lane) * 8);
    wf[j][1] = *(const short8*)(w1p + (size_t)(((n * 16 + np) * 2 + 1) * 64 + lane) * 8);
    bv[j]    = *(const short4v*)(b1p + (size_t)((n * 16 + np) * 64 + lane) * 4);
  }

  // stream 4 rowtiles: only in-loop global reads are x (independent per rt)
#pragma unroll
  for (int r = 0; r < 4; ++r) {
    const int rt = rtg * 4 + r;
    const float* px = x + (size_t)(rt * 16 + l15) * 1024 + n * 64 + lhi * 8;
    floatx4 a0 = *(const floatx4*)px;
    floatx4 a1 = *(const floatx4*)(px + 4);
    floatx4 a2 = *(const floatx4*)(px + 32);
    floatx4 a3 = *(const floatx4*)(px + 36);
    short8 xf0, xf1;
#pragma unroll
    for (int e = 0; e < 4; ++e) {
      xf0[e] = f2bf(a0[e]); xf0[e + 4] = f2bf(a1[e]);
      xf1[e] = f2bf(a2[e]); xf1[e + 4] = f2bf(a3[e]);
    }
    short* gb = G + (size_t)rt * 65536 + n * 256 + l15 * 16 + lhi * 4;
#pragma unroll
    for (int j = 0; j < 8; ++j) {
      floatx4 acc = {0.f, 0.f, 0.f, 0.f};
      acc = __builtin_amdgcn_mfma_f32_16x16x32_bf16(wf[j][0], xf0, acc, 0, 0, 0);
      acc = __builtin_amdgcn_mfma_f32_16x16x32_bf16(wf[j][1], xf1, acc, 0, 0, 0);
      short4v hv;
#pragma unroll
      for (int e = 0; e < 4; ++e)
        hv[e] = f2bf(gelu_f(acc[e] + bf2f(bv[j][e])));
      *(short4v*)(gb + (size_t)(np0 + j) * 4096) = hv;  // 512B/wave contiguous
    }
  }
}

// ---- K2: g -> y, 2048 WGs x 256 thr, wave = (rt, np)  [unchanged from R4] ----
__global__ __launch_bounds__(256, 4) void k2_gemm2(
    const short* __restrict__ G, const short* __restrict__ w2p,
    const float* __restrict__ b2, float* __restrict__ y) {
  const int tid = threadIdx.x;
  const int wv = tid >> 6, lane = tid & 63;
  const int l15 = lane & 15, lhi = lane >> 4;
  const int rt = blockIdx.x >> 2;
  const int np = (blockIdx.x & 3) * 4 + wv;

  const short* ab = G + (size_t)(rt * 16 + np) * 4096 + (lhi >> 1) * 256 + l15 * 16 + (lhi & 1) * 8;
  short8 af[8];
#pragma unroll
  for (int ks = 0; ks < 8; ++ks)
    af[ks] = *(const short8*)(ab + ks * 512);

#pragma unroll
  for (int ot = 0; ot < 4; ++ot) {
    floatx4 a0 = {0.f, 0.f, 0.f, 0.f}, a1 = {0.f, 0.f, 0.f, 0.f};
#pragma unroll
    for (int ks = 0; ks < 8; ks += 2) {
      short8 b0  = *(const short8*)(w2p + (size_t)(((np * 8 + ks) * 4 + ot) * 64 + lane) * 8);
      short8 b1f = *(const short8*)(w2p + (size_t)(((np * 8 + ks + 1) * 4 + ot) * 64 + lane) * 8);
      a0 = __builtin_amdgcn_mfma_f32_16x16x32_bf16(af[ks], b0, a0, 0, 0, 0);
      a1 = __builtin_amdgcn_mfma_f32_16x16x32_bf16(af[ks + 1], b1f, a1, 0, 0, 0);
    }
    const int col = np * 64 + ot * 16 + l15;
    const float bb = b2[col];
    float* py = y + (size_t)(rt * 16 + lhi * 4) * 1024 + col;
#pragma unroll
    for (int r = 0; r < 4; ++r)
      py[(size_t)r * 1024] = a0[r] + a1[r] + bb;
  }
}

extern "C" void kernel_launch(void* const* d_in, const int* in_sizes, int n_in,
                              void* d_out, int out_size, void* d_ws, size_t ws_size,
                              hipStream_t stream) {
  const float* x  = (const float*)d_in[0];
  const float* w1 = (const float*)d_in[1];
  const float* b1 = (const float*)d_in[2];
  const float* w2 = (const float*)d_in[3];
  const float* b2 = (const float*)d_in[4];
  float* y = (float*)d_out;

  short* w1p = (short*)d_ws;               // 512 KB
  short* w2p = w1p + 16 * 256 * 64;        // 512 KB
  short* b1p = w2p + 16 * 256 * 64;        // 128 KB
  short* G   = b1p + 16 * 16 * 64 * 4;     // 64 MB

  pack_k<<<160, 512, 0, stream>>>(w1, w2, b1, w1p, w2p, b1p);
  k1_gemm1<<<1024, 256, 0, stream>>>(x, w1p, b1p, G);
  k2_gemm2<<<2048, 256, 0, stream>>>(G, w2p, b2, y);
}